// Round 2
// baseline (517.431 us; speedup 1.0000x reference)
//
#include <hip/hip_runtime.h>
#include <hip/hip_cooperative_groups.h>

namespace cg = cooperative_groups;

typedef __attribute__((ext_vector_type(8))) short short8;
typedef __attribute__((ext_vector_type(4))) short short4v;
typedef __attribute__((ext_vector_type(8))) signed char s8x8;
typedef __attribute__((ext_vector_type(4))) unsigned char u8x4;
typedef __attribute__((ext_vector_type(4))) float f32x4;
typedef __attribute__((ext_vector_type(4))) int int4v;
typedef __attribute__((ext_vector_type(4))) unsigned int u32x4;

#define THRE 4.0f

#define GLOAD_LDS16(g, l) \
    __builtin_amdgcn_global_load_lds((const __attribute__((address_space(1))) void*)(g), \
                                     (__attribute__((address_space(3))) void*)(l), 16, 0, 0)

__device__ __forceinline__ float spikef(float x) {
    return floorf(fminf(fmaxf(x, 0.0f), THRE) + 0.5f);
}
__device__ __forceinline__ unsigned short f2bf(float f) {   // truncate; exact for small ints
    return (unsigned short)(__builtin_bit_cast(unsigned int, f) >> 16);
}
__device__ __forceinline__ unsigned short f2bf_rn(float f) { // round-to-nearest
    unsigned u = __builtin_bit_cast(unsigned int, f);
    unsigned r = ((u >> 16) & 1u) + 0x7FFFu;
    return (unsigned short)((u + r) >> 16);
}
__device__ __forceinline__ float bf2f(unsigned short s) {
    return __builtin_bit_cast(float, (unsigned int)s << 16);
}
__device__ __forceinline__ int4v mfma_i8(u32x4 a, u32x4 b, int4v c) {
    return __builtin_amdgcn_mfma_i32_16x16x64_i8(__builtin_bit_cast(int4v, a),
                                                 __builtin_bit_cast(int4v, b), c, 0, 0, 0);
}

// ================= single cooperative mega-kernel: prep | qkv-gemm | bn+spike+pack | attn | proj =================
// Phases are verbatim ports of the previously-verified 5 kernels; grid.sync() between phases.
// 512 blocks x 256 threads, 2 blocks/CU co-resident (cooperative launch guarantees).
__global__ __launch_bounds__(256, 2) void k_mega(
    const float* __restrict__ x, const float* __restrict__ Wq,
    const float* __restrict__ gamma, const float* __restrict__ beta,
    const float* __restrict__ Wp, const float* __restrict__ bias,
    unsigned char* __restrict__ xs8, signed char* __restrict__ Wq8,
    float* __restrict__ wscale, short* __restrict__ Wpd,
    short* __restrict__ qkvb, float* __restrict__ psum, float* __restrict__ psq,
    unsigned char* __restrict__ qp, unsigned char* __restrict__ kp,
    unsigned char* __restrict__ vt, short* __restrict__ sout,
    float* __restrict__ out)
{
    __shared__ __align__(16) unsigned char SMEM[34816];   // union: P1 28K | P2 5.6K | P3 34K | P4 20K
    const int tid  = threadIdx.x;
    const int u    = blockIdx.x;
    const int lane = tid & 63, wv = tid >> 6;
    const int wy = wv >> 1, wx = wv & 1;
    const int quad = lane >> 4, l16 = lane & 15;

    // ---------------- P0: prep (x->i8 spike; Wqkv->i8 rowquant; Wproj->bf16 RN) ----------------
    for (int blk = u; blk < 2688; blk += 512) {
        if (blk < 2048) {                                    // x: 2097152 floats, 4/thread
            const int i = blk * 256 + tid;
            const float4 v = *(const float4*)&x[(size_t)i * 4];
            u8x4 o;
            o.x = (unsigned char)spikef(v.x);
            o.y = (unsigned char)spikef(v.y);
            o.z = (unsigned char)spikef(v.z);
            o.w = (unsigned char)spikef(v.w);
            *(u8x4*)&xs8[(size_t)i * 4] = o;
        } else if (blk < 2432) {                             // Wqkv: 1536 rows of 512
            const int row = (blk - 2048) * 4 + (tid >> 6);
            const int ln = tid & 63;
            const float* wr = Wq + (size_t)row * 512 + ln * 8;
            float wbuf[8];
            float mx = 0.f;
            #pragma unroll
            for (int i = 0; i < 8; ++i) { wbuf[i] = wr[i]; mx = fmaxf(mx, fabsf(wbuf[i])); }
            #pragma unroll
            for (int o = 32; o > 0; o >>= 1) mx = fmaxf(mx, __shfl_xor(mx, o, 64));
            const float inv = mx > 0.f ? 127.0f / mx : 0.f;
            s8x8 q;
            #pragma unroll
            for (int i = 0; i < 8; ++i) q[i] = (signed char)rintf(wbuf[i] * inv);
            *(s8x8*)&Wq8[(size_t)row * 512 + ln * 8] = q;
            if (ln == 0) wscale[row] = mx > 0.f ? mx / 127.0f : 0.f;
        } else {                                             // Wproj: 262144 floats, 4/thread
            const int i = (blk - 2432) * 256 + tid;
            const float4 v = *(const float4*)&Wp[(size_t)i * 4];
            short4v o;
            o.x = (short)f2bf_rn(v.x);
            o.y = (short)f2bf_rn(v.y);
            o.z = (short)f2bf_rn(v.z);
            o.w = (short)f2bf_rn(v.w);
            *(short4v*)&Wpd[(size_t)i * 4] = o;
        }
    }
    __threadfence();
    cg::this_grid().sync();

    // ---------------- P1: qkv GEMM (i8) M=4096 N=1536 K=512, BM=128 BN=96 ----------------
    {
        unsigned char* As = SMEM;            // 16 KB
        unsigned char* Bs = SMEM + 16384;    // 12 KB
        const int mtile = u & 31;
        const int m0 = mtile * 128, n0 = (u >> 5) * 96;
        const int N = 1536;

        int4v acc[4][3];
        #pragma unroll
        for (int i = 0; i < 4; ++i)
            #pragma unroll
            for (int j = 0; j < 3; ++j)
                #pragma unroll
                for (int r = 0; r < 4; ++r) acc[i][j][r] = 0;

        const unsigned char* gA[4]; unsigned char* lA[4];
        #pragma unroll
        for (int i = 0; i < 4; ++i) {
            int L = wv + 4 * i;
            int c = L * 64 + lane;
            int r = c >> 3, g = (c & 7) ^ (r & 7);
            gA[i] = xs8 + (size_t)(m0 + r) * 512 + g * 16;
            lA[i] = &As[(size_t)c * 16];
        }
        const unsigned char* gB[3]; unsigned char* lB[3];
        #pragma unroll
        for (int i = 0; i < 3; ++i) {
            int L = wv + 4 * i;
            int c = L * 64 + lane;
            int r = c >> 3, g = (c & 7) ^ (r & 7);
            gB[i] = (const unsigned char*)Wq8 + (size_t)(n0 + r) * 512 + g * 16;
            lB[i] = &Bs[(size_t)c * 16];
        }

        for (int k0 = 0; k0 < 512; k0 += 128) {
            __syncthreads();
            #pragma unroll
            for (int i = 0; i < 4; ++i) GLOAD_LDS16(gA[i] + k0, lA[i]);
            #pragma unroll
            for (int i = 0; i < 3; ++i) GLOAD_LDS16(gB[i] + k0, lB[i]);
            __syncthreads();
            #pragma unroll
            for (int kk = 0; kk < 2; ++kk) {
                u32x4 aF[4], bF[3];
                #pragma unroll
                for (int mt = 0; mt < 4; ++mt) {
                    const int r = wy * 64 + mt * 16 + l16;
                    aF[mt] = *(const u32x4*)&As[(size_t)r * 128 + (((kk * 4 + quad) ^ (r & 7)) * 16)];
                }
                #pragma unroll
                for (int nt = 0; nt < 3; ++nt) {
                    const int r = wx * 48 + nt * 16 + l16;
                    bF[nt] = *(const u32x4*)&Bs[(size_t)r * 128 + (((kk * 4 + quad) ^ (r & 7)) * 16)];
                }
                #pragma unroll
                for (int mt = 0; mt < 4; ++mt)
                    #pragma unroll
                    for (int nt = 0; nt < 3; ++nt)
                        acc[mt][nt] = mfma_i8(aF[mt], bF[nt], acc[mt][nt]);
            }
        }

        float sc[3];
        #pragma unroll
        for (int nt = 0; nt < 3; ++nt) sc[nt] = wscale[n0 + wx * 48 + nt * 16 + l16];

        float vacc[4][3][4];
        #pragma unroll
        for (int mt = 0; mt < 4; ++mt)
            #pragma unroll
            for (int r = 0; r < 4; ++r) {
                int row = m0 + wy * 64 + mt * 16 + quad * 4 + r;
                short* Cr = qkvb + (size_t)row * N + n0 + wx * 48 + l16;
                #pragma unroll
                for (int nt = 0; nt < 3; ++nt) {
                    float v = (float)acc[mt][nt][r] * sc[nt];
                    vacc[mt][nt][r] = v;
                    Cr[nt * 16] = (short)f2bf_rn(v);
                }
            }

        __syncthreads();
        float* PS = (float*)As;   // [8][96]
        float* PQ = (float*)Bs;
        #pragma unroll
        for (int nt = 0; nt < 3; ++nt) {
            float s = 0.f, q = 0.f;
            #pragma unroll
            for (int mt = 0; mt < 4; ++mt)
                #pragma unroll
                for (int r = 0; r < 4; ++r) {
                    float v = vacc[mt][nt][r];
                    s += v;
                    q = fmaf(v, v, q);
                }
            PS[(wy * 4 + quad) * 96 + wx * 48 + nt * 16 + l16] = s;
            PQ[(wy * 4 + quad) * 96 + wx * 48 + nt * 16 + l16] = q;
        }
        __syncthreads();
        if (tid < 96) {
            float s = 0.f, q = 0.f;
            #pragma unroll
            for (int i = 0; i < 8; ++i) { s += PS[i * 96 + tid]; q += PQ[i * 96 + tid]; }
            psum[mtile * 1536 + n0 + tid] = s;
            psq [mtile * 1536 + n0 + tid] = q;
        }
    }
    __threadfence();
    cg::this_grid().sync();

    // ---------------- P2: BN finalize + spike + pack (384 of 512 blocks active) ----------------
    if (u < 384) {
        float* sa = (float*)SMEM;
        float* sb = sa + 64;
        unsigned char* tile = SMEM + 512;            // 64*80
        const int slice = u % 24;
        const int c0 = slice * 64;
        const int r0 = (u / 24) * 256;
        const int b = r0 >> 10, nb = r0 & 1023;

        if (tid < 64) {
            const int c = c0 + tid;
            double s = 0.0, q = 0.0;
            for (int st = 0; st < 32; ++st) { s += (double)psum[st * 1536 + c]; q += (double)psq[st * 1536 + c]; }
            const double mu  = s / 4096.0;
            const double var = q / 4096.0 - mu * mu;
            const float a = (float)((double)gamma[c] / sqrt(var + 1e-5));
            sa[tid] = a;
            sb[tid] = fmaf(-(float)mu, a, beta[c]);
        }
        __syncthreads();

        if (slice < 16) {
            const int h = slice & 7;
            const int ch4 = (tid & 15) * 4, rr = tid >> 4;     // 4 ch/thread, 16 rows/pass
            const float4 A4 = *(const float4*)&sa[ch4];
            const float4 B4 = *(const float4*)&sb[ch4];
            unsigned char* base = (slice < 8 ? qp : kp) + (((size_t)b * 8 + h) * 1024 + nb) * 64;
            for (int i = rr; i < 256; i += 16) {
                const short4v v4 = *(const short4v*)&qkvb[(size_t)(r0 + i) * 1536 + c0 + ch4];
                u8x4 o;
                o.x = (unsigned char)spikef(fmaf(bf2f((unsigned short)v4.x), A4.x, B4.x));
                o.y = (unsigned char)spikef(fmaf(bf2f((unsigned short)v4.y), A4.y, B4.y));
                o.z = (unsigned char)spikef(fmaf(bf2f((unsigned short)v4.z), A4.z, B4.z));
                o.w = (unsigned char)spikef(fmaf(bf2f((unsigned short)v4.w), A4.w, B4.w));
                *(u8x4*)&base[(size_t)i * 64 + ch4] = o;
            }
        } else {
            const int h = slice - 16;
            const int ch = tid & 63, rq = tid >> 6;
            const float A = sa[ch], Bsh = sb[ch];
            const int e = tid >> 2, j0 = (tid & 3) * 16;
            // fragment-linear target: bh*65536 + (nb>>8)*16384 + rb*4096 + d*64 + j
            unsigned char* vbase = vt + (size_t)b * 524288 + (size_t)h * 65536
                                 + (size_t)(nb >> 8) * 16384 + e * 64 + j0;
            for (int rb = 0; rb < 4; ++rb) {
                __syncthreads();
                for (int i = rq; i < 64; i += 4) {
                    float v = bf2f((unsigned short)qkvb[(size_t)(r0 + rb * 64 + i) * 1536 + c0 + ch]);
                    tile[ch * 80 + i] = (unsigned char)spikef(fmaf(v, A, Bsh));
                }
                __syncthreads();
                *(u32x4*)&vbase[rb * 4096] = *(const u32x4*)&tile[e * 80 + j0];
            }
        }
    }
    __threadfence();
    cg::this_grid().sync();

    // ---------------- P3: fused i8-MFMA attention (direct-global fragments, dbuf S) ----------------
    {
        unsigned int* Sb = (unsigned int*)SMEM;         // [2][64*68] dwords = 34816 B
        const int bhid = u & 31;
        const int b = bhid >> 3, h = bhid & 7;
        const int n0 = (u >> 5) * 64;
        const size_t bh = (size_t)b * 8 + h;

        const unsigned char* Kb = kp + bh * 65536;     // [n][64]
        const unsigned char* Vb = vt + bh * 65536;     // fragment-linear

        u32x4 qf[4];
        #pragma unroll
        for (int mt = 0; mt < 4; ++mt)
            qf[mt] = *(const u32x4*)&qp[(bh * 1024 + n0 + mt * 16 + l16) * 64 + quad * 16];

        int4v of[4];
        #pragma unroll
        for (int mt = 0; mt < 4; ++mt)
            #pragma unroll
            for (int r = 0; r < 4; ++r) of[mt][r] = 0;

        u32x4 kfc[4];
        #pragma unroll
        for (int jt = 0; jt < 4; ++jt)
            kfc[jt] = *(const u32x4*)&Kb[(size_t)(wv * 64 + jt * 16 + l16) * 64 + quad * 16];

        #pragma unroll
        for (int t = 0; t < 4; ++t) {
            u32x4 bV[4];
            #pragma unroll
            for (int kk = 0; kk < 4; ++kk)
                bV[kk] = *(const u32x4*)&Vb[(size_t)((t * 4 + kk) * 64 + wv * 16 + l16) * 64 + quad * 16];

            unsigned int* SbW = Sb + (t & 1) * 4352;
            __builtin_amdgcn_s_setprio(1);
            #pragma unroll
            for (int jt = 0; jt < 4; ++jt) {
                #pragma unroll
                for (int mt = 0; mt < 4; ++mt) {
                    int4v z;
                    #pragma unroll
                    for (int r = 0; r < 4; ++r) z[r] = 0;
                    int4v s = mfma_i8(kfc[jt], qf[mt], z);
                    unsigned int pkk = 0;
                    #pragma unroll
                    for (int r = 0; r < 4; ++r) {
                        int v = s[r]; v = v < 0 ? 0 : (v > 4 ? 4 : v);
                        pkk |= (unsigned int)v << (8 * r);
                    }
                    SbW[(mt * 16 + l16) * 68 + wv * 16 + jt * 4 + quad] = pkk;
                }
            }
            __builtin_amdgcn_s_setprio(0);
            __syncthreads();

            if (t < 3) {
                #pragma unroll
                for (int jt = 0; jt < 4; ++jt)
                    kfc[jt] = *(const u32x4*)&Kb[(size_t)((t + 1) * 256 + wv * 64 + jt * 16 + l16) * 64 + quad * 16];
            }

            __builtin_amdgcn_s_setprio(1);
            #pragma unroll
            for (int kk = 0; kk < 4; ++kk) {
                #pragma unroll
                for (int mt = 0; mt < 4; ++mt) {
                    u32x4 aS = *(const u32x4*)&SbW[(mt * 16 + l16) * 68 + kk * 16 + quad * 4];
                    of[mt] = mfma_i8(aS, bV[kk], of[mt]);
                }
            }
            __builtin_amdgcn_s_setprio(0);
        }

        #pragma unroll
        for (int mt = 0; mt < 4; ++mt)
            #pragma unroll
            for (int r = 0; r < 4; ++r) {
                size_t orow = (size_t)b * 1024 + n0 + mt * 16 + quad * 4 + r;
                sout[orow * 512 + h * 64 + wv * 16 + l16] =
                    (short)f2bf(spikef((float)of[mt][r] * 0.125f));
            }
    }
    __threadfence();
    cg::this_grid().sync();

    // ---------------- P4: proj GEMM (bf16) M=4096 N=512 K=512 ----------------
    {
        short* As = (short*)SMEM;            // 4 KB
        short* Bs = (short*)(SMEM + 4096);   // 16 KB
        const int mtile = u & 127;
        const int m0 = mtile * 32, n0 = (u >> 7) * 128;
        const int K = 512, N = 512;

        f32x4 acc[4];
        #pragma unroll
        for (int j = 0; j < 4; ++j)
            #pragma unroll
            for (int r = 0; r < 4; ++r) acc[j][r] = 0.f;

        const short* gA0; short* lA0;
        {
            int c = tid;
            int r = c >> 3, g = (c & 7) ^ (r & 7);
            gA0 = sout + (size_t)(m0 + r) * K + g * 8;
            lA0 = &As[(size_t)c * 8];
        }
        const short* gB[4]; short* lB[4];
        #pragma unroll
        for (int i = 0; i < 4; ++i) {
            int c = tid + 256 * i;
            int r = c >> 3, g = (c & 7) ^ (r & 7);
            gB[i] = Wpd + (size_t)(n0 + r) * K + g * 8;
            lB[i] = &Bs[(size_t)c * 8];
        }

        for (int k0 = 0; k0 < K; k0 += 64) {
            __syncthreads();
            GLOAD_LDS16(gA0 + k0, lA0);
            #pragma unroll
            for (int i = 0; i < 4; ++i) GLOAD_LDS16(gB[i] + k0, lB[i]);
            __syncthreads();
            #pragma unroll
            for (int kk = 0; kk < 2; ++kk) {
                const int ra = wy * 16 + l16;
                short8 aF = *(const short8*)&As[(size_t)ra * 64 + (((kk * 4 + quad) ^ (ra & 7)) * 8)];
                #pragma unroll
                for (int nt = 0; nt < 4; ++nt) {
                    const int rb = wx * 64 + nt * 16 + l16;
                    short8 bF = *(const short8*)&Bs[(size_t)rb * 64 + (((kk * 4 + quad) ^ (rb & 7)) * 8)];
                    acc[nt] = __builtin_amdgcn_mfma_f32_16x16x32_bf16(aF, bF, acc[nt], 0, 0, 0);
                }
            }
        }

        float bs[4];
        #pragma unroll
        for (int nt = 0; nt < 4; ++nt) bs[nt] = bias[n0 + wx * 64 + nt * 16 + l16];
        #pragma unroll
        for (int r = 0; r < 4; ++r) {
            int row = m0 + wy * 16 + quad * 4 + r;
            float* Cr = out + (size_t)row * N + n0 + wx * 64 + l16;
            #pragma unroll
            for (int nt = 0; nt < 4; ++nt) Cr[nt * 16] = acc[nt][r] + bs[nt];
        }
    }
}

extern "C" void kernel_launch(void* const* d_in, const int* in_sizes, int n_in,
                              void* d_out, int out_size, void* d_ws, size_t ws_size,
                              hipStream_t stream) {
    const float* x     = (const float*)d_in[0];
    const float* Wqkv  = (const float*)d_in[1];
    const float* gamma = (const float*)d_in[2];
    const float* beta  = (const float*)d_in[3];
    const float* Wproj = (const float*)d_in[4];
    const float* bproj = (const float*)d_in[5];
    float* out = (float*)d_out;

    char* w = (char*)d_ws;
    unsigned char* xs8   = (unsigned char*)(w);             // 2 MB; region reused as sout (4 MB)
    signed char* Wq8     = (signed char*)(w + 8388608);     // 0.75 MB
    float* wscale        = (float*)(w + 9437184);           // 6 KB
    short* Wproj2        = (short*)(w + 11534336);          // 0.5 MB
    short* qkvb          = (short*)(w + 12582912);          // 12 MB (bf16)
    unsigned char* qp    = (unsigned char*)(w + 37748736);  // 2 MB
    unsigned char* kp    = (unsigned char*)(w + 41943040);  // 2 MB
    unsigned char* vt    = (unsigned char*)(w + 46137344);  // 2 MB
    float* psum          = (float*)(w + 50331648);
    float* psq           = psum + 32 * 1536;
    short* sout          = (short*)(w);                     // xs8 dead after qkv GEMM

    void* args[] = { (void*)&x, (void*)&Wqkv, (void*)&gamma, (void*)&beta,
                     (void*)&Wproj, (void*)&bproj,
                     (void*)&xs8, (void*)&Wq8, (void*)&wscale, (void*)&Wproj2,
                     (void*)&qkvb, (void*)&psum, (void*)&psq,
                     (void*)&qp, (void*)&kp, (void*)&vt, (void*)&sout, (void*)&out };
    hipLaunchCooperativeKernel((const void*)k_mega, dim3(512), dim3(256), args, 0u, stream);
}

// Round 3
// 204.199 us; speedup vs baseline: 2.5340x; 2.5340x over previous
//
#include <hip/hip_runtime.h>

typedef __attribute__((ext_vector_type(8))) short short8;
typedef __attribute__((ext_vector_type(4))) short short4v;
typedef __attribute__((ext_vector_type(4))) float f32x4;
typedef __attribute__((ext_vector_type(4))) int int4v;
typedef __attribute__((ext_vector_type(4))) unsigned int u32x4;

#define THRE 4.0f

#define GLOAD_LDS16(g, l) \
    __builtin_amdgcn_global_load_lds((const __attribute__((address_space(1))) void*)(g), \
                                     (__attribute__((address_space(3))) void*)(l), 16, 0, 0)

__device__ __forceinline__ float spikef(float x) {
    return floorf(fminf(fmaxf(x, 0.0f), THRE) + 0.5f);
}
__device__ __forceinline__ unsigned short f2bf(float f) {   // truncate; exact for small ints
    return (unsigned short)(__builtin_bit_cast(unsigned int, f) >> 16);
}
__device__ __forceinline__ unsigned short f2bf_rn(float f) { // round-to-nearest
    unsigned u = __builtin_bit_cast(unsigned int, f);
    unsigned r = ((u >> 16) & 1u) + 0x7FFFu;
    return (unsigned short)((u + r) >> 16);
}
__device__ __forceinline__ float bf2f(unsigned short s) {
    return __builtin_bit_cast(float, (unsigned int)s << 16);
}
__device__ __forceinline__ int4v mfma_i8(u32x4 a, u32x4 b, int4v c) {
    return __builtin_amdgcn_mfma_i32_16x16x64_i8(__builtin_bit_cast(int4v, a),
                                                 __builtin_bit_cast(int4v, b), c, 0, 0, 0);
}

// ======== K1: fused prep + qkv GEMM (i8): M=4096 N=1536 K=512, BM=128 BN=96 ========
// A-tile: spike(x) computed inline during staging (bit-identical to old xs8 bytes).
// B-tile: per-row max/127 quant computed inline (exact fp-max -> order-free; same bytes).
__global__ __launch_bounds__(256) void k_qkv(const float* __restrict__ x,
                                             const float* __restrict__ Wq,
                                             short* __restrict__ C,
                                             float* __restrict__ psum,
                                             float* __restrict__ psq) {
    __shared__ __align__(16) unsigned char As[128 * 128];  // 16 KB
    __shared__ __align__(16) unsigned char Bs[96 * 128];   // 12 KB
    __shared__ float invB[96], scB[96];
    const int tid  = threadIdx.x;
    const int lane = tid & 63, wv = tid >> 6;
    const int wy = wv >> 1, wx = wv & 1;
    const int quad = lane >> 4, l16 = lane & 15;
    const int u = blockIdx.x;
    const int mtile = u & 31;                      // XCD = u%8; same-mtile blocks share XCD
    const int m0 = mtile * 128, n0 = (u >> 5) * 96;
    const int N = 1536;

    // ---- B row-max (exact max; any reduce order gives identical bits) ----
    #pragma unroll
    for (int rr = 0; rr < 3; ++rr) {
        const int row = rr * 32 + (tid >> 3);      // 0..95
        const int ln8 = tid & 7;
        const float* wr = Wq + (size_t)(n0 + row) * 512 + ln8 * 64;
        float mx = 0.f;
        #pragma unroll
        for (int i = 0; i < 16; ++i) {
            const float4 f = *(const float4*)(wr + i * 4);
            mx = fmaxf(mx, fmaxf(fmaxf(fabsf(f.x), fabsf(f.y)), fmaxf(fabsf(f.z), fabsf(f.w))));
        }
        mx = fmaxf(mx, __shfl_xor(mx, 1, 64));
        mx = fmaxf(mx, __shfl_xor(mx, 2, 64));
        mx = fmaxf(mx, __shfl_xor(mx, 4, 64));
        if (ln8 == 0) {
            invB[row] = mx > 0.f ? 127.0f / mx : 0.f;
            scB[row]  = mx > 0.f ? mx / 127.0f : 0.f;
        }
    }
    __syncthreads();

    int4v acc[4][3];
    #pragma unroll
    for (int i = 0; i < 4; ++i)
        #pragma unroll
        for (int j = 0; j < 3; ++j)
            #pragma unroll
            for (int r = 0; r < 4; ++r) acc[i][j][r] = 0;

    for (int k0 = 0; k0 < 512; k0 += 128) {
        __syncthreads();
        // A granules: spike(x) -> i8, same swizzled LDS layout as before
        #pragma unroll
        for (int i = 0; i < 4; ++i) {
            const int c = (wv + 4 * i) * 64 + lane;
            const int r = c >> 3, g = (c & 7) ^ (r & 7);
            const float* src = x + (size_t)(m0 + r) * 512 + k0 + g * 16;
            u32x4 ov;
            #pragma unroll
            for (int d = 0; d < 4; ++d) {
                const float4 f = *(const float4*)(src + d * 4);
                unsigned dw  = (unsigned)(unsigned char)spikef(f.x);
                dw |= (unsigned)(unsigned char)spikef(f.y) << 8;
                dw |= (unsigned)(unsigned char)spikef(f.z) << 16;
                dw |= (unsigned)(unsigned char)spikef(f.w) << 24;
                ov[d] = dw;
            }
            *(u32x4*)&As[(size_t)c * 16] = ov;
        }
        // B granules: rint(w*inv) -> s8
        #pragma unroll
        for (int i = 0; i < 3; ++i) {
            const int c = (wv + 4 * i) * 64 + lane;
            const int r = c >> 3, g = (c & 7) ^ (r & 7);
            const float* src = Wq + (size_t)(n0 + r) * 512 + k0 + g * 16;
            const float inv = invB[r];
            u32x4 ov;
            #pragma unroll
            for (int d = 0; d < 4; ++d) {
                const float4 f = *(const float4*)(src + d * 4);
                unsigned dw  = ((unsigned)(int)rintf(f.x * inv)) & 255u;
                dw |= (((unsigned)(int)rintf(f.y * inv)) & 255u) << 8;
                dw |= (((unsigned)(int)rintf(f.z * inv)) & 255u) << 16;
                dw |= (((unsigned)(int)rintf(f.w * inv)) & 255u) << 24;
                ov[d] = dw;
            }
            *(u32x4*)&Bs[(size_t)c * 16] = ov;
        }
        __syncthreads();
        #pragma unroll
        for (int kk = 0; kk < 2; ++kk) {
            u32x4 aF[4], bF[3];
            #pragma unroll
            for (int mt = 0; mt < 4; ++mt) {
                const int r = wy * 64 + mt * 16 + l16;
                aF[mt] = *(const u32x4*)&As[(size_t)r * 128 + (((kk * 4 + quad) ^ (r & 7)) * 16)];
            }
            #pragma unroll
            for (int nt = 0; nt < 3; ++nt) {
                const int r = wx * 48 + nt * 16 + l16;
                bF[nt] = *(const u32x4*)&Bs[(size_t)r * 128 + (((kk * 4 + quad) ^ (r & 7)) * 16)];
            }
            #pragma unroll
            for (int mt = 0; mt < 4; ++mt)
                #pragma unroll
                for (int nt = 0; nt < 3; ++nt)
                    acc[mt][nt] = mfma_i8(aF[mt], bF[nt], acc[mt][nt]);
        }
    }

    float sc[3];
    #pragma unroll
    for (int nt = 0; nt < 3; ++nt) sc[nt] = scB[wx * 48 + nt * 16 + l16];

    float vacc[4][3][4];
    #pragma unroll
    for (int mt = 0; mt < 4; ++mt)
        #pragma unroll
        for (int r = 0; r < 4; ++r) {
            int row = m0 + wy * 64 + mt * 16 + quad * 4 + r;
            short* Cr = C + (size_t)row * N + n0 + wx * 48 + l16;
            #pragma unroll
            for (int nt = 0; nt < 3; ++nt) {
                float v = (float)acc[mt][nt][r] * sc[nt];
                vacc[mt][nt][r] = v;
                Cr[nt * 16] = (short)f2bf_rn(v);
            }
        }

    __syncthreads();
    float* PS = (float*)As;   // [8][96]
    float* PQ = (float*)Bs;
    #pragma unroll
    for (int nt = 0; nt < 3; ++nt) {
        float s = 0.f, q = 0.f;
        #pragma unroll
        for (int mt = 0; mt < 4; ++mt)
            #pragma unroll
            for (int r = 0; r < 4; ++r) {
                float v = vacc[mt][nt][r];
                s += v;
                q = fmaf(v, v, q);
            }
        PS[(wy * 4 + quad) * 96 + wx * 48 + nt * 16 + l16] = s;
        PQ[(wy * 4 + quad) * 96 + wx * 48 + nt * 16 + l16] = q;
    }
    __syncthreads();
    if (tid < 96) {
        float s = 0.f, q = 0.f;
        #pragma unroll
        for (int i = 0; i < 8; ++i) { s += PS[i * 96 + tid]; q += PQ[i * 96 + tid]; }
        psum[mtile * 1536 + n0 + tid] = s;
        psq [mtile * 1536 + n0 + tid] = q;
    }
}

// ======== K2: fused BN + spike + i8 attention (+Wproj->bf16 tail) ========
// Q,K fragments built in registers from qkvb; V via LDS transpose tile (stride 272).
__global__ __launch_bounds__(256) void k_attn2(const short* __restrict__ qkvb,
                                               const float* __restrict__ psum,
                                               const float* __restrict__ psq,
                                               const float* __restrict__ gamma,
                                               const float* __restrict__ beta,
                                               const float* __restrict__ Wp,
                                               short* __restrict__ Wpd,
                                               short* __restrict__ sout) {
    __shared__ __align__(16) float sa[192], sb[192];
    __shared__ __align__(16) unsigned char Vt[64 * 272];   // V^T tile [d][j], 17408 B
    __shared__ __align__(16) unsigned int Sbuf[64 * 68];   // S exchange, 17408 B
    const int tid  = threadIdx.x;
    const int lane = tid & 63, wv = tid >> 6;
    const int quad = lane >> 4, l16 = lane & 15;
    const int u = blockIdx.x;
    const int bhid = u & 31;                       // XCD = u%8 = bhid%8 -> qkvb slice L2-local
    const int b = bhid >> 3, h = bhid & 7;
    const int n0 = (u >> 5) * 64;
    const size_t qrow_base = (size_t)b * 1024;

    // Wproj -> bf16 (independent work, overlaps everything)
    {
        const int i = u * 256 + tid;
        const float2 f = *(const float2*)&Wp[(size_t)i * 2];
        ((unsigned*)Wpd)[i] = (unsigned)f2bf_rn(f.x) | ((unsigned)f2bf_rn(f.y) << 16);
    }

    // BN coefficients for this head's 192 channels (identical double math as before)
    if (tid < 192) {
        const int g = tid >> 6, cc = tid & 63;
        const int c = g * 512 + h * 64 + cc;
        double s = 0.0, q = 0.0;
        for (int st = 0; st < 32; ++st) { s += (double)psum[st * 1536 + c]; q += (double)psq[st * 1536 + c]; }
        const double mu  = s / 4096.0;
        const double var = q / 4096.0 - mu * mu;
        const float a = (float)((double)gamma[c] / sqrt(var + 1e-5));
        sa[tid] = a;
        sb[tid] = fmaf(-(float)mu, a, beta[c]);
    }
    __syncthreads();

    // per-lane BN coeffs for Q (ch quad*16..) and K (ch 512 + quad*16..)
    f32x4 aQ[4], bQ[4], aK[4], bK[4];
    #pragma unroll
    for (int d = 0; d < 4; ++d) {
        aQ[d] = *(const f32x4*)&sa[quad * 16 + d * 4];
        bQ[d] = *(const f32x4*)&sb[quad * 16 + d * 4];
        aK[d] = *(const f32x4*)&sa[64 + quad * 16 + d * 4];
        bK[d] = *(const f32x4*)&sb[64 + quad * 16 + d * 4];
    }
    const int vch = tid >> 2;                      // V build: this thread's d-channel
    const int vj0 = (tid & 3) * 4;
    const float aV = sa[128 + vch], bV0 = sb[128 + vch];
    const short* vsrc = qkvb + 1024 + h * 64 + vch;

    // Q fragments in registers
    u32x4 qf[4];
    #pragma unroll
    for (int mt = 0; mt < 4; ++mt) {
        const short* src = qkvb + (qrow_base + n0 + mt * 16 + l16) * 1536 + h * 64 + quad * 16;
        const short8 v0 = *(const short8*)src;
        const short8 v1 = *(const short8*)(src + 8);
        u32x4 r;
        #pragma unroll
        for (int d = 0; d < 4; ++d) {
            unsigned dw = 0;
            #pragma unroll
            for (int j = 0; j < 4; ++j) {
                const int idx = d * 4 + j;
                const float f = bf2f((unsigned short)(idx < 8 ? v0[idx] : v1[idx - 8]));
                dw |= (unsigned)(unsigned char)spikef(fmaf(f, aQ[d][j], bQ[d][j])) << (8 * j);
            }
            r[d] = dw;
        }
        qf[mt] = r;
    }

    int4v of[4];
    #pragma unroll
    for (int mt = 0; mt < 4; ++mt)
        #pragma unroll
        for (int r = 0; r < 4; ++r) of[mt][r] = 0;

    for (int t = 0; t < 4; ++t) {
        __syncthreads();                            // Vt/Sbuf free (prev tile consumed)
        // ---- V^T tile build: thread owns channel vch, writes packed 4-j dwords ----
        {
            const short* bt = vsrc + (qrow_base + t * 256) * 1536;
            #pragma unroll
            for (int k = 0; k < 16; ++k) {
                unsigned dw = 0;
                #pragma unroll
                for (int i = 0; i < 4; ++i) {
                    const int j = vj0 + k * 16 + i;
                    const float f = bf2f((unsigned short)bt[(size_t)j * 1536]);
                    dw |= (unsigned)(unsigned char)spikef(fmaf(f, aV, bV0)) << (8 * i);
                }
                *(unsigned*)&Vt[vch * 272 + vj0 + k * 16] = dw;
            }
        }
        // ---- K fragments in registers ----
        u32x4 kf[4];
        #pragma unroll
        for (int jt = 0; jt < 4; ++jt) {
            const short* src = qkvb + (qrow_base + t * 256 + wv * 64 + jt * 16 + l16) * 1536
                             + 512 + h * 64 + quad * 16;
            const short8 v0 = *(const short8*)src;
            const short8 v1 = *(const short8*)(src + 8);
            u32x4 r;
            #pragma unroll
            for (int d = 0; d < 4; ++d) {
                unsigned dw = 0;
                #pragma unroll
                for (int j = 0; j < 4; ++j) {
                    const int idx = d * 4 + j;
                    const float f = bf2f((unsigned short)(idx < 8 ? v0[idx] : v1[idx - 8]));
                    dw |= (unsigned)(unsigned char)spikef(fmaf(f, aK[d][j], bK[d][j])) << (8 * j);
                }
                r[d] = dw;
            }
            kf[jt] = r;
        }
        __syncthreads();                            // Vt ready

        // ---- QK^T -> clamp-spike -> Sbuf ----
        __builtin_amdgcn_s_setprio(1);
        #pragma unroll
        for (int jt = 0; jt < 4; ++jt) {
            #pragma unroll
            for (int mt = 0; mt < 4; ++mt) {
                int4v z;
                #pragma unroll
                for (int r = 0; r < 4; ++r) z[r] = 0;
                int4v s = mfma_i8(kf[jt], qf[mt], z);
                unsigned pkk = 0;
                #pragma unroll
                for (int r = 0; r < 4; ++r) {
                    int v = s[r]; v = v < 0 ? 0 : (v > 4 ? 4 : v);
                    pkk |= (unsigned)v << (8 * r);
                }
                Sbuf[(mt * 16 + l16) * 68 + wv * 16 + jt * 4 + quad] = pkk;
            }
        }
        __builtin_amdgcn_s_setprio(0);
        __syncthreads();                            // Sbuf ready (Vt still valid)

        // ---- PV ----
        __builtin_amdgcn_s_setprio(1);
        #pragma unroll
        for (int kk = 0; kk < 4; ++kk) {
            const u32x4 bVf = *(const u32x4*)&Vt[(wv * 16 + l16) * 272 + (kk * 4 + quad) * 16];
            #pragma unroll
            for (int mt = 0; mt < 4; ++mt) {
                const u32x4 aS = *(const u32x4*)&Sbuf[(mt * 16 + l16) * 68 + kk * 16 + quad * 4];
                of[mt] = mfma_i8(aS, bVf, of[mt]);
            }
        }
        __builtin_amdgcn_s_setprio(0);
    }

    #pragma unroll
    for (int mt = 0; mt < 4; ++mt)
        #pragma unroll
        for (int r = 0; r < 4; ++r) {
            size_t orow = qrow_base + n0 + mt * 16 + quad * 4 + r;
            sout[orow * 512 + h * 64 + wv * 16 + l16] =
                (short)f2bf(spikef((float)of[mt][r] * 0.125f));
        }
}

// ======== K3: proj GEMM (bf16): M=4096 N=512 K=512 — unchanged ========
__global__ __launch_bounds__(256) void k_gemm_proj(const short* __restrict__ A,
                                                   const short* __restrict__ B,
                                                   const float* __restrict__ bias,
                                                   float* __restrict__ C) {
    __shared__ __align__(16) short As[32 * 64];    // 4 KB
    __shared__ __align__(16) short Bs[128 * 64];   // 16 KB
    const int tid  = threadIdx.x;
    const int lane = tid & 63, wv = tid >> 6;
    const int wy = wv >> 1, wx = wv & 1;
    const int quad = lane >> 4, l16 = lane & 15;
    const int u = blockIdx.x;
    const int mtile = u & 127;                     // XCD = u%8 = mtile%8
    const int m0 = mtile * 32, n0 = (u >> 7) * 128;
    const int K = 512, N = 512;

    f32x4 acc[4];
    #pragma unroll
    for (int j = 0; j < 4; ++j)
        #pragma unroll
        for (int r = 0; r < 4; ++r) acc[j][r] = 0.f;

    const short* gA0; short* lA0;
    {
        int c = tid;
        int r = c >> 3, g = (c & 7) ^ (r & 7);
        gA0 = A + (size_t)(m0 + r) * K + g * 8;
        lA0 = &As[(size_t)c * 8];
    }
    const short* gB[4]; short* lB[4];
    #pragma unroll
    for (int i = 0; i < 4; ++i) {
        int c = tid + 256 * i;
        int r = c >> 3, g = (c & 7) ^ (r & 7);
        gB[i] = B + (size_t)(n0 + r) * K + g * 8;
        lB[i] = &Bs[(size_t)c * 8];
    }

    for (int k0 = 0; k0 < K; k0 += 64) {
        __syncthreads();
        GLOAD_LDS16(gA0 + k0, lA0);
        #pragma unroll
        for (int i = 0; i < 4; ++i) GLOAD_LDS16(gB[i] + k0, lB[i]);
        __syncthreads();
        #pragma unroll
        for (int kk = 0; kk < 2; ++kk) {
            const int ra = wy * 16 + l16;
            short8 aF = *(const short8*)&As[(size_t)ra * 64 + (((kk * 4 + quad) ^ (ra & 7)) * 8)];
            #pragma unroll
            for (int nt = 0; nt < 4; ++nt) {
                const int rb = wx * 64 + nt * 16 + l16;
                short8 bF = *(const short8*)&Bs[(size_t)rb * 64 + (((kk * 4 + quad) ^ (rb & 7)) * 8)];
                acc[nt] = __builtin_amdgcn_mfma_f32_16x16x32_bf16(aF, bF, acc[nt], 0, 0, 0);
            }
        }
    }

    float bs[4];
    #pragma unroll
    for (int nt = 0; nt < 4; ++nt) bs[nt] = bias[n0 + wx * 64 + nt * 16 + l16];
    #pragma unroll
    for (int r = 0; r < 4; ++r) {
        int row = m0 + wy * 16 + quad * 4 + r;
        float* Cr = C + (size_t)row * N + n0 + wx * 64 + l16;
        #pragma unroll
        for (int nt = 0; nt < 4; ++nt) Cr[nt * 16] = acc[nt][r] + bs[nt];
    }
}

extern "C" void kernel_launch(void* const* d_in, const int* in_sizes, int n_in,
                              void* d_out, int out_size, void* d_ws, size_t ws_size,
                              hipStream_t stream) {
    const float* x     = (const float*)d_in[0];
    const float* Wqkv  = (const float*)d_in[1];
    const float* gamma = (const float*)d_in[2];
    const float* beta  = (const float*)d_in[3];
    const float* Wproj = (const float*)d_in[4];
    const float* bproj = (const float*)d_in[5];
    float* out = (float*)d_out;

    char* w = (char*)d_ws;
    short* Wpd           = (short*)(w + 11534336);          // 0.5 MB
    short* qkvb          = (short*)(w + 12582912);          // 12 MB (bf16)
    float* psum          = (float*)(w + 50331648);
    float* psq           = psum + 32 * 1536;
    short* sout          = (short*)(w);                     // 4 MB

    k_qkv  <<<512, 256, 0, stream>>>(x, Wqkv, qkvb, psum, psq);
    k_attn2<<<512, 256, 0, stream>>>(qkvb, psum, psq, gamma, beta, Wproj, Wpd, sout);
    k_gemm_proj<<<512, 256, 0, stream>>>(sout, Wpd, bproj, out);
}

// Round 4
// 126.684 us; speedup vs baseline: 4.0844x; 1.6119x over previous
//
#include <hip/hip_runtime.h>

typedef __attribute__((ext_vector_type(8))) short short8;
typedef __attribute__((ext_vector_type(4))) short short4v;
typedef __attribute__((ext_vector_type(4))) unsigned char u8x4;
typedef __attribute__((ext_vector_type(4))) float f32x4;
typedef __attribute__((ext_vector_type(4))) int int4v;
typedef __attribute__((ext_vector_type(4))) unsigned int u32x4;

#define THRE 4.0f

#define GLOAD_LDS16(g, l) \
    __builtin_amdgcn_global_load_lds((const __attribute__((address_space(1))) void*)(g), \
                                     (__attribute__((address_space(3))) void*)(l), 16, 0, 0)

__device__ __forceinline__ float spikef(float x) {
    return floorf(fminf(fmaxf(x, 0.0f), THRE) + 0.5f);
}
__device__ __forceinline__ unsigned short f2bf(float f) {   // truncate; exact for small ints
    return (unsigned short)(__builtin_bit_cast(unsigned int, f) >> 16);
}
__device__ __forceinline__ unsigned short f2bf_rn(float f) { // round-to-nearest
    unsigned u = __builtin_bit_cast(unsigned int, f);
    unsigned r = ((u >> 16) & 1u) + 0x7FFFu;
    return (unsigned short)((u + r) >> 16);
}
__device__ __forceinline__ float bf2f(unsigned short s) {
    return __builtin_bit_cast(float, (unsigned int)s << 16);
}
__device__ __forceinline__ int4v mfma_i8(u32x4 a, u32x4 b, int4v c) {
    return __builtin_amdgcn_mfma_i32_16x16x64_i8(__builtin_bit_cast(int4v, a),
                                                 __builtin_bit_cast(int4v, b), c, 0, 0, 0);
}

// ======== K1: fused prep + qkv GEMM (i8): M=4096 N=1536 K=512, BM=128 BN=96 ========
// B panel: converted ONCE per block into resident 48KB LDS (coalesced prologue).
// A tile: converted per k-step from registers prefetched under previous step's MFMA (T14).
// All bytes bit-identical to the round-1 prep outputs.
__global__ __launch_bounds__(256, 2) void k_qkv(const float* __restrict__ x,
                                                const float* __restrict__ Wq,
                                                short* __restrict__ C,
                                                float* __restrict__ psum,
                                                float* __restrict__ psq) {
    __shared__ __align__(16) unsigned char As[128 * 128];   // 16 KB, per-step A tile
    __shared__ __align__(16) unsigned char Bs[96 * 512];    // 48 KB, resident B panel
    __shared__ float invB[96], scB[96];
    const int tid  = threadIdx.x;
    const int lane = tid & 63, wv = tid >> 6;
    const int wy = wv >> 1, wx = wv & 1;
    const int quad = lane >> 4, l16 = lane & 15;
    const int u = blockIdx.x;
    const int mtile = u & 31;                      // XCD = u%8; same-mtile blocks share XCD
    const int m0 = mtile * 128, n0 = (u >> 5) * 96;
    const int N = 1536;

    // ---- B row-max (exact fp max; order-free; identical to round-3's verified code) ----
    #pragma unroll
    for (int rr = 0; rr < 3; ++rr) {
        const int row = rr * 32 + (tid >> 3);      // 0..95
        const int ln8 = tid & 7;
        const float* wr = Wq + (size_t)(n0 + row) * 512 + ln8 * 64;
        float mx = 0.f;
        #pragma unroll
        for (int i = 0; i < 16; ++i) {
            const float4 f = *(const float4*)(wr + i * 4);
            mx = fmaxf(mx, fmaxf(fmaxf(fabsf(f.x), fabsf(f.y)), fmaxf(fabsf(f.z), fabsf(f.w))));
        }
        mx = fmaxf(mx, __shfl_xor(mx, 1, 64));
        mx = fmaxf(mx, __shfl_xor(mx, 2, 64));
        mx = fmaxf(mx, __shfl_xor(mx, 4, 64));
        if (ln8 == 0) {
            invB[row] = mx > 0.f ? 127.0f / mx : 0.f;
            scB[row]  = mx > 0.f ? mx / 127.0f : 0.f;
        }
    }
    __syncthreads();

    // ---- B panel -> i8, swizzled so the k-loop reads are identical to round 1 ----
    // For source granule ks (16B) of row r: slot = (ks&~7) | ((ks&7)^(r&7)).
    #pragma unroll
    for (int i = 0; i < 12; ++i) {
        const int idx = i * 256 + tid;             // 0..3071 granules
        const int r = idx >> 5, ks = idx & 31;
        const float* src = Wq + (size_t)(n0 + r) * 512 + ks * 16;
        const float inv = invB[r];
        u32x4 ov;
        #pragma unroll
        for (int d = 0; d < 4; ++d) {
            const float4 f = *(const float4*)(src + d * 4);
            unsigned dw  = ((unsigned)(int)rintf(f.x * inv)) & 255u;
            dw |= (((unsigned)(int)rintf(f.y * inv)) & 255u) << 8;
            dw |= (((unsigned)(int)rintf(f.z * inv)) & 255u) << 16;
            dw |= (((unsigned)(int)rintf(f.w * inv)) & 255u) << 24;
            ov[d] = dw;
        }
        *(u32x4*)&Bs[(size_t)r * 512 + (((ks & ~7) | ((ks & 7) ^ (r & 7))) * 16)] = ov;
    }

    // ---- A prefetch for step 0 (16 float4 = 64 floats/thread) ----
    float4 aPre[16];
    #pragma unroll
    for (int i = 0; i < 4; ++i) {
        const int idx = i * 256 + tid;             // 0..1023 granules
        const int r = idx >> 3, q = idx & 7;
        const float* src = x + (size_t)(m0 + r) * 512 + q * 16;
        #pragma unroll
        for (int d = 0; d < 4; ++d) aPre[i * 4 + d] = *(const float4*)(src + d * 4);
    }

    int4v acc[4][3];
    #pragma unroll
    for (int i = 0; i < 4; ++i)
        #pragma unroll
        for (int j = 0; j < 3; ++j)
            #pragma unroll
            for (int r = 0; r < 4; ++r) acc[i][j][r] = 0;

    for (int t = 0; t < 4; ++t) {
        __syncthreads();                           // As free (prev consumed); Bs ready at t=0
        // pack prefetched A regs -> spike i8 -> swizzled LDS
        #pragma unroll
        for (int i = 0; i < 4; ++i) {
            const int idx = i * 256 + tid;
            const int r = idx >> 3, q = idx & 7;
            u32x4 ov;
            #pragma unroll
            for (int d = 0; d < 4; ++d) {
                const float4 f = aPre[i * 4 + d];
                unsigned dw  = (unsigned)(unsigned char)spikef(f.x);
                dw |= (unsigned)(unsigned char)spikef(f.y) << 8;
                dw |= (unsigned)(unsigned char)spikef(f.z) << 16;
                dw |= (unsigned)(unsigned char)spikef(f.w) << 24;
                ov[d] = dw;
            }
            *(u32x4*)&As[(size_t)r * 128 + ((q ^ (r & 7)) * 16)] = ov;
        }
        __syncthreads();
        // issue next step's A loads; they fly under this step's MFMA
        if (t < 3) {
            const int k0n = (t + 1) * 128;
            #pragma unroll
            for (int i = 0; i < 4; ++i) {
                const int idx = i * 256 + tid;
                const int r = idx >> 3, q = idx & 7;
                const float* src = x + (size_t)(m0 + r) * 512 + k0n + q * 16;
                #pragma unroll
                for (int d = 0; d < 4; ++d) aPre[i * 4 + d] = *(const float4*)(src + d * 4);
            }
        }
        const int k0 = t * 128;
        #pragma unroll
        for (int kk = 0; kk < 2; ++kk) {
            u32x4 aF[4], bF[3];
            #pragma unroll
            for (int mt = 0; mt < 4; ++mt) {
                const int r = wy * 64 + mt * 16 + l16;
                aF[mt] = *(const u32x4*)&As[(size_t)r * 128 + (((kk * 4 + quad) ^ (r & 7)) * 16)];
            }
            #pragma unroll
            for (int nt = 0; nt < 3; ++nt) {
                const int r = wx * 48 + nt * 16 + l16;
                bF[nt] = *(const u32x4*)&Bs[(size_t)r * 512 + k0 + (((kk * 4 + quad) ^ (r & 7)) * 16)];
            }
            #pragma unroll
            for (int mt = 0; mt < 4; ++mt)
                #pragma unroll
                for (int nt = 0; nt < 3; ++nt)
                    acc[mt][nt] = mfma_i8(aF[mt], bF[nt], acc[mt][nt]);
        }
    }

    float sc[3];
    #pragma unroll
    for (int nt = 0; nt < 3; ++nt) sc[nt] = scB[wx * 48 + nt * 16 + l16];

    float vacc[4][3][4];
    #pragma unroll
    for (int mt = 0; mt < 4; ++mt)
        #pragma unroll
        for (int r = 0; r < 4; ++r) {
            int row = m0 + wy * 64 + mt * 16 + quad * 4 + r;
            short* Cr = C + (size_t)row * N + n0 + wx * 48 + l16;
            #pragma unroll
            for (int nt = 0; nt < 3; ++nt) {
                float v = (float)acc[mt][nt][r] * sc[nt];
                vacc[mt][nt][r] = v;
                Cr[nt * 16] = (short)f2bf_rn(v);
            }
        }

    __syncthreads();
    float* PS = (float*)As;   // [8][96]
    float* PQ = (float*)Bs;
    #pragma unroll
    for (int nt = 0; nt < 3; ++nt) {
        float s = 0.f, q = 0.f;
        #pragma unroll
        for (int mt = 0; mt < 4; ++mt)
            #pragma unroll
            for (int r = 0; r < 4; ++r) {
                float v = vacc[mt][nt][r];
                s += v;
                q = fmaf(v, v, q);
            }
        PS[(wy * 4 + quad) * 96 + wx * 48 + nt * 16 + l16] = s;
        PQ[(wy * 4 + quad) * 96 + wx * 48 + nt * 16 + l16] = q;
    }
    __syncthreads();
    if (tid < 96) {
        float s = 0.f, q = 0.f;
        #pragma unroll
        for (int i = 0; i < 8; ++i) { s += PS[i * 96 + tid]; q += PQ[i * 96 + tid]; }
        psum[mtile * 1536 + n0 + tid] = s;
        psq [mtile * 1536 + n0 + tid] = q;
    }
}

// ======== K2: BN finalize + spike + pack (round-1 verbatim) + Wproj->bf16 rider ========
// vt layout: [bh][t=j/256][kk=(j/64)%4][d=0..63][quad=(j/16)%4][16B j-bytes]
__global__ __launch_bounds__(256) void k_bn_spike(const short* __restrict__ qkvb,
                           const float* __restrict__ psum, const float* __restrict__ psq,
                           const float* __restrict__ gamma, const float* __restrict__ beta,
                           unsigned char* __restrict__ qp, unsigned char* __restrict__ kp,
                           unsigned char* __restrict__ vt,
                           const float* __restrict__ Wp, short* __restrict__ Wpd) {
    __shared__ float sa[64], sb[64];
    __shared__ __align__(16) unsigned char tile[64 * 80];
    const int tid = threadIdx.x;
    const int slice = blockIdx.x;            // 0..23
    const int c0 = slice * 64;
    const int r0 = blockIdx.y * 256;
    const int b = r0 >> 10, nb = r0 & 1023;

    // Wproj -> bf16 rider: 262144 floats over first 65536 threads, 4 each, coalesced
    {
        const int gid = (blockIdx.y * 24 + blockIdx.x) * 256 + tid;
        if (gid < 65536) {
            const float4 v = *(const float4*)&Wp[(size_t)gid * 4];
            short4v o;
            o.x = (short)f2bf_rn(v.x);
            o.y = (short)f2bf_rn(v.y);
            o.z = (short)f2bf_rn(v.z);
            o.w = (short)f2bf_rn(v.w);
            *(short4v*)&Wpd[(size_t)gid * 4] = o;
        }
    }

    if (tid < 64) {
        const int c = c0 + tid;
        double s = 0.0, q = 0.0;
        for (int st = 0; st < 32; ++st) { s += (double)psum[st * 1536 + c]; q += (double)psq[st * 1536 + c]; }
        const double mu  = s / 4096.0;
        const double var = q / 4096.0 - mu * mu;
        const float a = (float)((double)gamma[c] / sqrt(var + 1e-5));
        sa[tid] = a;
        sb[tid] = fmaf(-(float)mu, a, beta[c]);
    }
    __syncthreads();

    if (slice < 16) {
        const int h = slice & 7;
        const int ch4 = (tid & 15) * 4, rr = tid >> 4;     // 4 ch/thread, 16 rows/pass
        const float4 A4 = *(const float4*)&sa[ch4];
        const float4 B4 = *(const float4*)&sb[ch4];
        unsigned char* base = (slice < 8 ? qp : kp) + (((size_t)b * 8 + h) * 1024 + nb) * 64;
        for (int i = rr; i < 256; i += 16) {
            const short4v v4 = *(const short4v*)&qkvb[(size_t)(r0 + i) * 1536 + c0 + ch4];
            u8x4 o;
            o.x = (unsigned char)spikef(fmaf(bf2f((unsigned short)v4.x), A4.x, B4.x));
            o.y = (unsigned char)spikef(fmaf(bf2f((unsigned short)v4.y), A4.y, B4.y));
            o.z = (unsigned char)spikef(fmaf(bf2f((unsigned short)v4.z), A4.z, B4.z));
            o.w = (unsigned char)spikef(fmaf(bf2f((unsigned short)v4.w), A4.w, B4.w));
            *(u8x4*)&base[(size_t)i * 64 + ch4] = o;
        }
    } else {
        const int h = slice - 16;
        const int ch = tid & 63, rq = tid >> 6;
        const float A = sa[ch], Bsh = sb[ch];
        const int e = tid >> 2, j0 = (tid & 3) * 16;
        // fragment-linear target: bh*65536 + (nb>>8)*16384 + rb*4096 + d*64 + j
        unsigned char* vbase = vt + (size_t)b * 524288 + (size_t)h * 65536
                             + (size_t)(nb >> 8) * 16384 + e * 64 + j0;
        for (int rb = 0; rb < 4; ++rb) {
            __syncthreads();
            for (int i = rq; i < 64; i += 4) {
                float v = bf2f((unsigned short)qkvb[(size_t)(r0 + rb * 64 + i) * 1536 + c0 + ch]);
                tile[ch * 80 + i] = (unsigned char)spikef(fmaf(v, A, Bsh));
            }
            __syncthreads();
            *(u32x4*)&vbase[rb * 4096] = *(const u32x4*)&tile[e * 80 + j0];
        }
    }
}

// ======== K3: fused i8-MFMA attention (round-1 verbatim: direct-global fragments, dbuf S) ========
__global__ __launch_bounds__(256) void k_attn(const unsigned char* __restrict__ qp,
                                              const unsigned char* __restrict__ kp,
                                              const unsigned char* __restrict__ vt,
                                              short* __restrict__ sout) {
    __shared__ __align__(16) unsigned int Sb[2][64 * 68];   // 34 KB double-buffered S exchange
    const int tid  = threadIdx.x;
    const int lane = tid & 63, w = tid >> 6;
    const int quad = lane >> 4, l16 = lane & 15;
    const int u = blockIdx.x;
    const int bhid = u & 31;                       // XCD = u%8 = bhid%8 -> K/V L2-local
    const int b = bhid >> 3, h = bhid & 7;
    const int n0 = (u >> 5) * 64;
    const size_t bh = (size_t)b * 8 + h;

    const unsigned char* Kb = kp + bh * 65536;     // [n][64]
    const unsigned char* Vb = vt + bh * 65536;     // fragment-linear

    u32x4 qf[4];
    #pragma unroll
    for (int mt = 0; mt < 4; ++mt)
        qf[mt] = *(const u32x4*)&qp[(bh * 1024 + n0 + mt * 16 + l16) * 64 + quad * 16];

    int4v of[4];
    #pragma unroll
    for (int mt = 0; mt < 4; ++mt)
        #pragma unroll
        for (int r = 0; r < 4; ++r) of[mt][r] = 0;

    u32x4 kfc[4];
    #pragma unroll
    for (int jt = 0; jt < 4; ++jt)
        kfc[jt] = *(const u32x4*)&Kb[(size_t)(w * 64 + jt * 16 + l16) * 64 + quad * 16];

    #pragma unroll
    for (int t = 0; t < 4; ++t) {
        u32x4 bV[4];
        #pragma unroll
        for (int kk = 0; kk < 4; ++kk)
            bV[kk] = *(const u32x4*)&Vb[(size_t)((t * 4 + kk) * 64 + w * 16 + l16) * 64 + quad * 16];

        __builtin_amdgcn_s_setprio(1);
        #pragma unroll
        for (int jt = 0; jt < 4; ++jt) {
            #pragma unroll
            for (int mt = 0; mt < 4; ++mt) {
                int4v z;
                #pragma unroll
                for (int r = 0; r < 4; ++r) z[r] = 0;
                int4v s = mfma_i8(kfc[jt], qf[mt], z);
                unsigned int pkk = 0;
                #pragma unroll
                for (int r = 0; r < 4; ++r) {
                    int v = s[r]; v = v < 0 ? 0 : (v > 4 ? 4 : v);
                    pkk |= (unsigned int)v << (8 * r);
                }
                Sb[t & 1][(mt * 16 + l16) * 68 + w * 16 + jt * 4 + quad] = pkk;
            }
        }
        __builtin_amdgcn_s_setprio(0);
        __syncthreads();

        if (t < 3) {
            #pragma unroll
            for (int jt = 0; jt < 4; ++jt)
                kfc[jt] = *(const u32x4*)&Kb[(size_t)((t + 1) * 256 + w * 64 + jt * 16 + l16) * 64 + quad * 16];
        }

        __builtin_amdgcn_s_setprio(1);
        #pragma unroll
        for (int kk = 0; kk < 4; ++kk) {
            #pragma unroll
            for (int mt = 0; mt < 4; ++mt) {
                u32x4 aS = *(const u32x4*)&Sb[t & 1][(mt * 16 + l16) * 68 + kk * 16 + quad * 4];
                of[mt] = mfma_i8(aS, bV[kk], of[mt]);
            }
        }
        __builtin_amdgcn_s_setprio(0);
    }

    #pragma unroll
    for (int mt = 0; mt < 4; ++mt)
        #pragma unroll
        for (int r = 0; r < 4; ++r) {
            size_t orow = (size_t)b * 1024 + n0 + mt * 16 + quad * 4 + r;
            sout[orow * 512 + h * 64 + w * 16 + l16] =
                (short)f2bf(spikef((float)of[mt][r] * 0.125f));
        }
}

// ======== K4: proj GEMM (bf16): M=4096 N=512 K=512 (round-1 verbatim) ========
__global__ __launch_bounds__(256) void k_gemm_proj(const short* __restrict__ A,
                                                   const short* __restrict__ B,
                                                   const float* __restrict__ bias,
                                                   float* __restrict__ C) {
    __shared__ __align__(16) short As[32 * 64];    // 4 KB
    __shared__ __align__(16) short Bs[128 * 64];   // 16 KB
    const int tid  = threadIdx.x;
    const int lane = tid & 63, wv = tid >> 6;
    const int wy = wv >> 1, wx = wv & 1;
    const int quad = lane >> 4, l16 = lane & 15;
    const int u = blockIdx.x;
    const int mtile = u & 127;                     // XCD = u%8 = mtile%8
    const int m0 = mtile * 32, n0 = (u >> 7) * 128;
    const int K = 512, N = 512;

    f32x4 acc[4];
    #pragma unroll
    for (int j = 0; j < 4; ++j)
        #pragma unroll
        for (int r = 0; r < 4; ++r) acc[j][r] = 0.f;

    const short* gA0; short* lA0;
    {
        int c = tid;
        int r = c >> 3, g = (c & 7) ^ (r & 7);
        gA0 = A + (size_t)(m0 + r) * K + g * 8;
        lA0 = &As[(size_t)c * 8];
    }
    const short* gB[4]; short* lB[4];
    #pragma unroll
    for (int i = 0; i < 4; ++i) {
        int c = tid + 256 * i;
        int r = c >> 3, g = (c & 7) ^ (r & 7);
        gB[i] = B + (size_t)(n0 + r) * K + g * 8;
        lB[i] = &Bs[(size_t)c * 8];
    }

    for (int k0 = 0; k0 < K; k0 += 64) {
        __syncthreads();
        GLOAD_LDS16(gA0 + k0, lA0);
        #pragma unroll
        for (int i = 0; i < 4; ++i) GLOAD_LDS16(gB[i] + k0, lB[i]);
        __syncthreads();
        #pragma unroll
        for (int kk = 0; kk < 2; ++kk) {
            const int ra = wy * 16 + l16;
            short8 aF = *(const short8*)&As[(size_t)ra * 64 + (((kk * 4 + quad) ^ (ra & 7)) * 8)];
            #pragma unroll
            for (int nt = 0; nt < 4; ++nt) {
                const int rb = wx * 64 + nt * 16 + l16;
                short8 bF = *(const short8*)&Bs[(size_t)rb * 64 + (((kk * 4 + quad) ^ (rb & 7)) * 8)];
                acc[nt] = __builtin_amdgcn_mfma_f32_16x16x32_bf16(aF, bF, acc[nt], 0, 0, 0);
            }
        }
    }

    float bs[4];
    #pragma unroll
    for (int nt = 0; nt < 4; ++nt) bs[nt] = bias[n0 + wx * 64 + nt * 16 + l16];
    #pragma unroll
    for (int r = 0; r < 4; ++r) {
        int row = m0 + wy * 16 + quad * 4 + r;
        float* Cr = C + (size_t)row * N + n0 + wx * 64 + l16;
        #pragma unroll
        for (int nt = 0; nt < 4; ++nt) Cr[nt * 16] = acc[nt][r] + bs[nt];
    }
}

extern "C" void kernel_launch(void* const* d_in, const int* in_sizes, int n_in,
                              void* d_out, int out_size, void* d_ws, size_t ws_size,
                              hipStream_t stream) {
    const float* x     = (const float*)d_in[0];
    const float* Wqkv  = (const float*)d_in[1];
    const float* gamma = (const float*)d_in[2];
    const float* beta  = (const float*)d_in[3];
    const float* Wproj = (const float*)d_in[4];
    const float* bproj = (const float*)d_in[5];
    float* out = (float*)d_out;

    char* w = (char*)d_ws;
    short* Wpd           = (short*)(w + 11534336);          // 0.5 MB
    short* qkvb          = (short*)(w + 12582912);          // 12 MB (bf16)
    unsigned char* qp    = (unsigned char*)(w + 37748736);  // 2 MB
    unsigned char* kp    = (unsigned char*)(w + 41943040);  // 2 MB
    unsigned char* vt    = (unsigned char*)(w + 46137344);  // 2 MB
    float* psum          = (float*)(w + 50331648);
    float* psq           = psum + 32 * 1536;
    short* sout          = (short*)(w);                     // 4 MB

    k_qkv      <<<512, 256, 0, stream>>>(x, Wqkv, qkvb, psum, psq);
    k_bn_spike <<<dim3(24, 16), 256, 0, stream>>>(qkvb, psum, psq, gamma, beta, qp, kp, vt, Wproj, Wpd);
    k_attn     <<<512, 256, 0, stream>>>(qp, kp, vt, sout);
    k_gemm_proj<<<512, 256, 0, stream>>>(sout, Wpd, bproj, out);
}

// Round 5
// 103.776 us; speedup vs baseline: 4.9860x; 1.2207x over previous
//
#include <hip/hip_runtime.h>

typedef __attribute__((ext_vector_type(8))) short short8;
typedef __attribute__((ext_vector_type(4))) short short4v;
typedef __attribute__((ext_vector_type(8))) signed char s8x8;
typedef __attribute__((ext_vector_type(4))) unsigned char u8x4;
typedef __attribute__((ext_vector_type(4))) float f32x4;
typedef __attribute__((ext_vector_type(4))) int int4v;
typedef __attribute__((ext_vector_type(4))) unsigned int u32x4;

#define THRE 4.0f

#define GLOAD_LDS16(g, l) \
    __builtin_amdgcn_global_load_lds((const __attribute__((address_space(1))) void*)(g), \
                                     (__attribute__((address_space(3))) void*)(l), 16, 0, 0)
#define WAIT_VM(n)  asm volatile("s_waitcnt vmcnt(" #n ")" ::: "memory")
#define WAIT_LGKM0  asm volatile("s_waitcnt lgkmcnt(0)" ::: "memory")
#define SBAR        __builtin_amdgcn_s_barrier()
#define SCHEDBAR    __builtin_amdgcn_sched_barrier(0)

__device__ __forceinline__ float spikef(float x) {
    return floorf(fminf(fmaxf(x, 0.0f), THRE) + 0.5f);
}
__device__ __forceinline__ unsigned short f2bf(float f) {   // truncate; exact for small ints
    return (unsigned short)(__builtin_bit_cast(unsigned int, f) >> 16);
}
__device__ __forceinline__ unsigned short f2bf_rn(float f) { // round-to-nearest
    unsigned u = __builtin_bit_cast(unsigned int, f);
    unsigned r = ((u >> 16) & 1u) + 0x7FFFu;
    return (unsigned short)((u + r) >> 16);
}
__device__ __forceinline__ float bf2f(unsigned short s) {
    return __builtin_bit_cast(float, (unsigned int)s << 16);
}
__device__ __forceinline__ int4v mfma_i8(u32x4 a, u32x4 b, int4v c) {
    return __builtin_amdgcn_mfma_i32_16x16x64_i8(__builtin_bit_cast(int4v, a),
                                                 __builtin_bit_cast(int4v, b), c, 0, 0, 0);
}

// ---------- prep: x -> i8 spike; Wqkv -> i8 per-row quant + scale ----------
__global__ void k_prep(const float* __restrict__ x, const float* __restrict__ Wq,
                       unsigned char* __restrict__ xs8, signed char* __restrict__ Wq8,
                       float* __restrict__ wscale) {
    const int blk = blockIdx.x, tid = threadIdx.x;
    if (blk < 2048) {                                    // x: 2097152 floats, 4/thread
        const int i = blk * 256 + tid;
        const float4 v = *(const float4*)&x[(size_t)i * 4];
        u8x4 o;
        o.x = (unsigned char)spikef(v.x);
        o.y = (unsigned char)spikef(v.y);
        o.z = (unsigned char)spikef(v.z);
        o.w = (unsigned char)spikef(v.w);
        *(u8x4*)&xs8[(size_t)i * 4] = o;
    } else {                                             // Wqkv: 1536 rows of 512
        const int row = (blk - 2048) * 4 + (tid >> 6);
        const int lane = tid & 63;
        const float* wr = Wq + (size_t)row * 512 + lane * 8;
        float w[8];
        float mx = 0.f;
        #pragma unroll
        for (int i = 0; i < 8; ++i) { w[i] = wr[i]; mx = fmaxf(mx, fabsf(w[i])); }
        #pragma unroll
        for (int o = 32; o > 0; o >>= 1) mx = fmaxf(mx, __shfl_xor(mx, o, 64));
        const float inv = mx > 0.f ? 127.0f / mx : 0.f;
        s8x8 q;
        #pragma unroll
        for (int i = 0; i < 8; ++i) q[i] = (signed char)rintf(w[i] * inv);
        *(s8x8*)&Wq8[(size_t)row * 512 + lane * 8] = q;
        if (lane == 0) wscale[row] = mx > 0.f ? mx / 127.0f : 0.f;
    }
}

// ---------- qkv GEMM (i8): M=4096 N=1536 K=512, dbuf LDS + counted vmcnt ----------
__global__ __launch_bounds__(256) void k_gemm_qkv(const unsigned char* __restrict__ A,
                                                  const signed char* __restrict__ B,
                                                  const float* __restrict__ wscale,
                                                  short* __restrict__ C,
                                                  float* __restrict__ psum,
                                                  float* __restrict__ psq) {
    __shared__ __align__(16) unsigned char As[2][128 * 128];  // 32 KB
    __shared__ __align__(16) unsigned char Bs[2][96 * 128];   // 24 KB
    const int tid  = threadIdx.x;
    const int lane = tid & 63, wv = tid >> 6;
    const int wy = wv >> 1, wx = wv & 1;
    const int quad = lane >> 4, l16 = lane & 15;
    const int u = blockIdx.x;
    const int mtile = u & 31;                      // XCD = u%8
    const int m0 = mtile * 128, n0 = (u >> 5) * 96;
    const int N = 1536;

    // anchor scale loads NOW so the k-loop's vmcnt ledger contains only glds ops
    float sc[3];
    #pragma unroll
    for (int nt = 0; nt < 3; ++nt) sc[nt] = wscale[n0 + wx * 48 + nt * 16 + l16];
    asm volatile("" :: "v"(sc[0]), "v"(sc[1]), "v"(sc[2]));

    int4v acc[4][3];
    #pragma unroll
    for (int i = 0; i < 4; ++i)
        #pragma unroll
        for (int j = 0; j < 3; ++j)
            #pragma unroll
            for (int r = 0; r < 4; ++r) acc[i][j][r] = 0;

    const unsigned char* gA[4]; int lA[4];
    #pragma unroll
    for (int i = 0; i < 4; ++i) {
        int c = (wv + 4 * i) * 64 + lane;
        int r = c >> 3, g = (c & 7) ^ (r & 7);
        gA[i] = A + (size_t)(m0 + r) * 512 + g * 16;
        lA[i] = c * 16;
    }
    const unsigned char* gB[3]; int lB[3];
    #pragma unroll
    for (int i = 0; i < 3; ++i) {
        int c = (wv + 4 * i) * 64 + lane;
        int r = c >> 3, g = (c & 7) ^ (r & 7);
        gB[i] = (const unsigned char*)B + (size_t)(n0 + r) * 512 + g * 16;
        lB[i] = c * 16;
    }

    // prologue: stage tile 0 -> buf 0
    #pragma unroll
    for (int i = 0; i < 4; ++i) GLOAD_LDS16(gA[i], &As[0][lA[i]]);
    #pragma unroll
    for (int i = 0; i < 3; ++i) GLOAD_LDS16(gB[i], &Bs[0][lB[i]]);

    for (int t = 0; t < 4; ++t) {
        if (t > 0) {           // WAR: all waves done computing t-1 before overwriting its buffer
            WAIT_LGKM0;
            SBAR;
        }
        if (t < 3) {           // stage t+1 -> other buffer; flies under this tile's compute
            const int k0n = (t + 1) * 128;
            const int bn = (t + 1) & 1;
            #pragma unroll
            for (int i = 0; i < 4; ++i) GLOAD_LDS16(gA[i] + k0n, &As[bn][lA[i]]);
            #pragma unroll
            for (int i = 0; i < 3; ++i) GLOAD_LDS16(gB[i] + k0n, &Bs[bn][lB[i]]);
            WAIT_VM(7);        // tile-t loads (issued one phase ago) complete
        } else {
            WAIT_VM(0);
        }
        SBAR;
        SCHEDBAR;
        const int bc = t & 1;
        #pragma unroll
        for (int kk = 0; kk < 2; ++kk) {
            u32x4 aF[4], bF[3];
            #pragma unroll
            for (int mt = 0; mt < 4; ++mt) {
                const int r = wy * 64 + mt * 16 + l16;
                aF[mt] = *(const u32x4*)&As[bc][(size_t)r * 128 + (((kk * 4 + quad) ^ (r & 7)) * 16)];
            }
            #pragma unroll
            for (int nt = 0; nt < 3; ++nt) {
                const int r = wx * 48 + nt * 16 + l16;
                bF[nt] = *(const u32x4*)&Bs[bc][(size_t)r * 128 + (((kk * 4 + quad) ^ (r & 7)) * 16)];
            }
            #pragma unroll
            for (int mt = 0; mt < 4; ++mt)
                #pragma unroll
                for (int nt = 0; nt < 3; ++nt)
                    acc[mt][nt] = mfma_i8(aF[mt], bF[nt], acc[mt][nt]);
        }
    }

    float vacc[4][3][4];
    #pragma unroll
    for (int mt = 0; mt < 4; ++mt)
        #pragma unroll
        for (int r = 0; r < 4; ++r) {
            int row = m0 + wy * 64 + mt * 16 + quad * 4 + r;
            short* Cr = C + (size_t)row * N + n0 + wx * 48 + l16;
            #pragma unroll
            for (int nt = 0; nt < 3; ++nt) {
                float v = (float)acc[mt][nt][r] * sc[nt];
                vacc[mt][nt][r] = v;
                Cr[nt * 16] = (short)f2bf_rn(v);
            }
        }

    __syncthreads();
    float* PS = (float*)&As[0][0];   // [8][96]
    float* PQ = (float*)&As[1][0];
    #pragma unroll
    for (int nt = 0; nt < 3; ++nt) {
        float s = 0.f, q = 0.f;
        #pragma unroll
        for (int mt = 0; mt < 4; ++mt)
            #pragma unroll
            for (int r = 0; r < 4; ++r) {
                float v = vacc[mt][nt][r];
                s += v;
                q = fmaf(v, v, q);
            }
        PS[(wy * 4 + quad) * 96 + wx * 48 + nt * 16 + l16] = s;
        PQ[(wy * 4 + quad) * 96 + wx * 48 + nt * 16 + l16] = q;
    }
    __syncthreads();
    if (tid < 96) {
        float s = 0.f, q = 0.f;
        #pragma unroll
        for (int i = 0; i < 8; ++i) { s += PS[i * 96 + tid]; q += PQ[i * 96 + tid]; }
        psum[mtile * 1536 + n0 + tid] = s;
        psq [mtile * 1536 + n0 + tid] = q;
    }
}

// ---------- BN finalize + spike + pack (vectorized) + Wproj->bf16 rider ----------
// vt layout: [bh][t=j/256][kk=(j/64)%4][d=0..63][quad=(j/16)%4][16B j-bytes]
__global__ __launch_bounds__(256) void k_bn_spike(const short* __restrict__ qkvb,
                           const float* __restrict__ psum, const float* __restrict__ psq,
                           const float* __restrict__ gamma, const float* __restrict__ beta,
                           unsigned char* __restrict__ qp, unsigned char* __restrict__ kp,
                           unsigned char* __restrict__ vt,
                           const float* __restrict__ Wp, short* __restrict__ Wpd) {
    __shared__ float sa[64], sb[64];
    __shared__ __align__(16) unsigned char tile[64 * 80];
    const int tid = threadIdx.x;
    const int slice = blockIdx.x;            // 0..23
    const int c0 = slice * 64;
    const int r0 = blockIdx.y * 256;
    const int b = r0 >> 10, nb = r0 & 1023;

    // Wproj -> bf16 rider: 262144 floats over first 65536 threads, 4 each, coalesced
    {
        const int gid = (blockIdx.y * 24 + blockIdx.x) * 256 + tid;
        if (gid < 65536) {
            const float4 v = *(const float4*)&Wp[(size_t)gid * 4];
            short4v o;
            o.x = (short)f2bf_rn(v.x);
            o.y = (short)f2bf_rn(v.y);
            o.z = (short)f2bf_rn(v.z);
            o.w = (short)f2bf_rn(v.w);
            *(short4v*)&Wpd[(size_t)gid * 4] = o;
        }
    }

    if (tid < 64) {
        const int c = c0 + tid;
        double s = 0.0, q = 0.0;
        for (int st = 0; st < 32; ++st) { s += (double)psum[st * 1536 + c]; q += (double)psq[st * 1536 + c]; }
        const double mu  = s / 4096.0;
        const double var = q / 4096.0 - mu * mu;
        const float a = (float)((double)gamma[c] / sqrt(var + 1e-5));
        sa[tid] = a;
        sb[tid] = fmaf(-(float)mu, a, beta[c]);
    }
    __syncthreads();

    const int ch8 = (tid & 7) * 8;
    float A8[8], B8[8];
    #pragma unroll
    for (int j = 0; j < 8; ++j) { A8[j] = sa[ch8 + j]; B8[j] = sb[ch8 + j]; }

    if (slice < 16) {
        const int h = slice & 7;
        const int rr = tid >> 3;                           // 32 rows/pass, 8 passes
        unsigned char* base = (slice < 8 ? qp : kp) + (((size_t)b * 8 + h) * 1024 + nb) * 64;
        for (int i = rr; i < 256; i += 32) {
            const short8 v8 = *(const short8*)&qkvb[(size_t)(r0 + i) * 1536 + c0 + ch8];
            unsigned lo = 0, hi = 0;
            #pragma unroll
            for (int j = 0; j < 4; ++j)
                lo |= (unsigned)(unsigned char)spikef(fmaf(bf2f((unsigned short)v8[j]), A8[j], B8[j])) << (8 * j);
            #pragma unroll
            for (int j = 0; j < 4; ++j)
                hi |= (unsigned)(unsigned char)spikef(fmaf(bf2f((unsigned short)v8[4 + j]), A8[4 + j], B8[4 + j])) << (8 * j);
            uint2 o; o.x = lo; o.y = hi;
            *(uint2*)&base[(size_t)i * 64 + ch8] = o;
        }
    } else {
        const int h = slice - 16;
        const int rw = tid >> 3;                           // 32 rows/pass
        const int e = tid >> 2, j0 = (tid & 3) * 16;
        // fragment-linear target: bh*65536 + (nb>>8)*16384 + rb*4096 + d*64 + j
        unsigned char* vbase = vt + (size_t)b * 524288 + (size_t)h * 65536
                             + (size_t)(nb >> 8) * 16384 + e * 64 + j0;
        for (int rb = 0; rb < 4; ++rb) {
            __syncthreads();
            #pragma unroll
            for (int p = 0; p < 2; ++p) {
                const int row = p * 32 + rw;
                const short8 v8 = *(const short8*)&qkvb[(size_t)(r0 + rb * 64 + row) * 1536 + c0 + ch8];
                #pragma unroll
                for (int j = 0; j < 8; ++j)
                    tile[(ch8 + j) * 80 + row] =
                        (unsigned char)spikef(fmaf(bf2f((unsigned short)v8[j]), A8[j], B8[j]));
            }
            __syncthreads();
            *(u32x4*)&vbase[rb * 4096] = *(const u32x4*)&tile[e * 80 + j0];
        }
    }
}

// ---------- fused i8-MFMA attention (round-1 verbatim: direct-global fragments, dbuf S) ----------
__global__ __launch_bounds__(256) void k_attn(const unsigned char* __restrict__ qp,
                                              const unsigned char* __restrict__ kp,
                                              const unsigned char* __restrict__ vt,
                                              short* __restrict__ sout) {
    __shared__ __align__(16) unsigned int Sb[2][64 * 68];   // 34 KB double-buffered S exchange
    const int tid  = threadIdx.x;
    const int lane = tid & 63, w = tid >> 6;
    const int quad = lane >> 4, l16 = lane & 15;
    const int u = blockIdx.x;
    const int bhid = u & 31;                       // XCD = u%8 = bhid%8 -> K/V L2-local
    const int b = bhid >> 3, h = bhid & 7;
    const int n0 = (u >> 5) * 64;
    const size_t bh = (size_t)b * 8 + h;

    const unsigned char* Kb = kp + bh * 65536;     // [n][64]
    const unsigned char* Vb = vt + bh * 65536;     // fragment-linear

    u32x4 qf[4];
    #pragma unroll
    for (int mt = 0; mt < 4; ++mt)
        qf[mt] = *(const u32x4*)&qp[(bh * 1024 + n0 + mt * 16 + l16) * 64 + quad * 16];

    int4v of[4];
    #pragma unroll
    for (int mt = 0; mt < 4; ++mt)
        #pragma unroll
        for (int r = 0; r < 4; ++r) of[mt][r] = 0;

    u32x4 kfc[4];
    #pragma unroll
    for (int jt = 0; jt < 4; ++jt)
        kfc[jt] = *(const u32x4*)&Kb[(size_t)(w * 64 + jt * 16 + l16) * 64 + quad * 16];

    #pragma unroll
    for (int t = 0; t < 4; ++t) {
        u32x4 bV[4];
        #pragma unroll
        for (int kk = 0; kk < 4; ++kk)
            bV[kk] = *(const u32x4*)&Vb[(size_t)((t * 4 + kk) * 64 + w * 16 + l16) * 64 + quad * 16];

        __builtin_amdgcn_s_setprio(1);
        #pragma unroll
        for (int jt = 0; jt < 4; ++jt) {
            #pragma unroll
            for (int mt = 0; mt < 4; ++mt) {
                int4v z;
                #pragma unroll
                for (int r = 0; r < 4; ++r) z[r] = 0;
                int4v s = mfma_i8(kfc[jt], qf[mt], z);
                unsigned int pkk = 0;
                #pragma unroll
                for (int r = 0; r < 4; ++r) {
                    int v = s[r]; v = v < 0 ? 0 : (v > 4 ? 4 : v);
                    pkk |= (unsigned int)v << (8 * r);
                }
                Sb[t & 1][(mt * 16 + l16) * 68 + w * 16 + jt * 4 + quad] = pkk;
            }
        }
        __builtin_amdgcn_s_setprio(0);
        __syncthreads();

        if (t < 3) {
            #pragma unroll
            for (int jt = 0; jt < 4; ++jt)
                kfc[jt] = *(const u32x4*)&Kb[(size_t)((t + 1) * 256 + w * 64 + jt * 16 + l16) * 64 + quad * 16];
        }

        __builtin_amdgcn_s_setprio(1);
        #pragma unroll
        for (int kk = 0; kk < 4; ++kk) {
            #pragma unroll
            for (int mt = 0; mt < 4; ++mt) {
                u32x4 aS = *(const u32x4*)&Sb[t & 1][(mt * 16 + l16) * 68 + kk * 16 + quad * 4];
                of[mt] = mfma_i8(aS, bV[kk], of[mt]);
            }
        }
        __builtin_amdgcn_s_setprio(0);
    }

    #pragma unroll
    for (int mt = 0; mt < 4; ++mt)
        #pragma unroll
        for (int r = 0; r < 4; ++r) {
            size_t orow = (size_t)b * 1024 + n0 + mt * 16 + quad * 4 + r;
            sout[orow * 512 + h * 64 + w * 16 + l16] =
                (short)f2bf(spikef((float)of[mt][r] * 0.125f));
        }
}

// ---------- proj GEMM (bf16): resident A panel + dbuf B, counted vmcnt ----------
__global__ __launch_bounds__(256) void k_gemm_proj(const short* __restrict__ A,
                                                   const short* __restrict__ B,
                                                   const float* __restrict__ bias,
                                                   float* __restrict__ C) {
    __shared__ __align__(16) short As[32 * 512];      // 32 KB resident A panel
    __shared__ __align__(16) short Bs[2][128 * 64];   // 32 KB dbuf B
    const int tid  = threadIdx.x;
    const int lane = tid & 63, wv = tid >> 6;
    const int wy = wv >> 1, wx = wv & 1;
    const int quad = lane >> 4, l16 = lane & 15;
    const int u = blockIdx.x;
    const int mtile = u & 127;                     // XCD = u%8 = mtile%8
    const int m0 = mtile * 32, n0 = (u >> 7) * 128;
    const int N = 512;

    // anchor bias loads so the k-loop vmcnt ledger is glds-only
    float bs[4];
    #pragma unroll
    for (int nt = 0; nt < 4; ++nt) bs[nt] = bias[n0 + wx * 64 + nt * 16 + l16];
    asm volatile("" :: "v"(bs[0]), "v"(bs[1]), "v"(bs[2]), "v"(bs[3]));

    f32x4 acc[4];
    #pragma unroll
    for (int j = 0; j < 4; ++j)
        #pragma unroll
        for (int r = 0; r < 4; ++r) acc[j][r] = 0.f;

    // A: 2048 granules (32 rows x 64), 8/thread; slot s8 of block kb holds global granule s8^(r&7)
    const short* gAg[8]; int lAo[8];
    #pragma unroll
    for (int i = 0; i < 8; ++i) {
        int c = tid + 256 * i;
        int r = c >> 6, slot = c & 63, kb = slot >> 3, s8 = slot & 7;
        gAg[i] = A + (size_t)(m0 + r) * 512 + (kb * 8 + (s8 ^ (r & 7))) * 8;
        lAo[i] = c * 8;
    }
    // B: 1024 granules/tile (128 rows x 8), 4/thread
    const short* gBg[4]; int lBo[4];
    #pragma unroll
    for (int i = 0; i < 4; ++i) {
        int c = tid + 256 * i;
        int r = c >> 3, s8 = c & 7;
        gBg[i] = B + (size_t)(n0 + r) * 512 + (s8 ^ (r & 7)) * 8;
        lBo[i] = c * 8;
    }

    // prologue: resident A + B tile 0
    #pragma unroll
    for (int i = 0; i < 8; ++i) GLOAD_LDS16(gAg[i], &As[lAo[i]]);
    #pragma unroll
    for (int i = 0; i < 4; ++i) GLOAD_LDS16(gBg[i], &Bs[0][lBo[i]]);

    for (int t = 0; t < 8; ++t) {
        if (t > 0) {           // WAR before overwriting the buffer tile t-1 used
            WAIT_LGKM0;
            SBAR;
        }
        if (t < 7) {
            const int bn = (t + 1) & 1;
            #pragma unroll
            for (int i = 0; i < 4; ++i) GLOAD_LDS16(gBg[i] + (t + 1) * 64, &Bs[bn][lBo[i]]);
            WAIT_VM(4);
        } else {
            WAIT_VM(0);
        }
        SBAR;
        SCHEDBAR;
        const int bc = t & 1;
        #pragma unroll
        for (int kk = 0; kk < 2; ++kk) {
            const int ra = wy * 16 + l16;
            short8 aF = *(const short8*)&As[(size_t)ra * 512 + t * 64 + (((kk * 4 + quad) ^ (ra & 7)) * 8)];
            #pragma unroll
            for (int nt = 0; nt < 4; ++nt) {
                const int rb = wx * 64 + nt * 16 + l16;
                short8 bF = *(const short8*)&Bs[bc][(size_t)rb * 64 + (((kk * 4 + quad) ^ (rb & 7)) * 8)];
                acc[nt] = __builtin_amdgcn_mfma_f32_16x16x32_bf16(aF, bF, acc[nt], 0, 0, 0);
            }
        }
    }

    #pragma unroll
    for (int r = 0; r < 4; ++r) {
        int row = m0 + wy * 16 + quad * 4 + r;
        float* Cr = C + (size_t)row * N + n0 + wx * 64 + l16;
        #pragma unroll
        for (int nt = 0; nt < 4; ++nt) Cr[nt * 16] = acc[nt][r] + bs[nt];
    }
}

extern "C" void kernel_launch(void* const* d_in, const int* in_sizes, int n_in,
                              void* d_out, int out_size, void* d_ws, size_t ws_size,
                              hipStream_t stream) {
    const float* x     = (const float*)d_in[0];
    const float* Wqkv  = (const float*)d_in[1];
    const float* gamma = (const float*)d_in[2];
    const float* beta  = (const float*)d_in[3];
    const float* Wproj = (const float*)d_in[4];
    const float* bproj = (const float*)d_in[5];
    float* out = (float*)d_out;

    char* w = (char*)d_ws;
    unsigned char* xs8   = (unsigned char*)(w);             // 2 MB; region reused as sout (4 MB)
    signed char* Wq8     = (signed char*)(w + 8388608);     // 0.75 MB
    float* wscale        = (float*)(w + 9437184);           // 6 KB
    short* Wpd           = (short*)(w + 11534336);          // 0.5 MB
    short* qkvb          = (short*)(w + 12582912);          // 12 MB (bf16)
    unsigned char* qp    = (unsigned char*)(w + 37748736);  // 2 MB
    unsigned char* kp    = (unsigned char*)(w + 41943040);  // 2 MB
    unsigned char* vt    = (unsigned char*)(w + 46137344);  // 2 MB
    float* psum          = (float*)(w + 50331648);
    float* psq           = psum + 32 * 1536;
    short* sout          = (short*)(w);                     // xs8 dead after qkv GEMM

    k_prep     <<<2432, 256, 0, stream>>>(x, Wqkv, xs8, Wq8, wscale);
    k_gemm_qkv <<<512, 256, 0, stream>>>(xs8, Wq8, wscale, qkvb, psum, psq);
    k_bn_spike <<<dim3(24, 16), 256, 0, stream>>>(qkvb, psum, psq, gamma, beta, qp, kp, vt, Wproj, Wpd);
    k_attn     <<<512, 256, 0, stream>>>(qp, kp, vt, sout);
    k_gemm_proj<<<512, 256, 0, stream>>>(sout, Wpd, bproj, out);
}